// Round 1
// baseline (93.585 us; speedup 1.0000x reference)
//
#include <hip/hip_runtime.h>
#include <math.h>

#define HW 128
#define NPTS 2048

constexpr float ZNEAR = 0.01f, ZFAR = 100.0f;
constexpr float EPS2D = 0.3f;
constexpr float ALPHA_CLIP = 0.999f;
constexpr float ALPHA_MIN = 1.0f / 255.0f;

// ws layout (floats):
//   un: 11 arrays * NPTS : [key, mx, my, cA, cB, cC, opac, z, r, g, b]
//   so: 10 arrays * NPTS : [mx, my, cA, cB, cC, opac, z, r, g, b]

__global__ void preprocess_kernel(const float* __restrict__ means,
                                  const float* __restrict__ quats,
                                  const float* __restrict__ scales,
                                  const float* __restrict__ opacities,
                                  const float* __restrict__ colors,
                                  const float* __restrict__ viewmat,
                                  const float* __restrict__ Kmat,
                                  float* __restrict__ un) {
  int i = blockIdx.x * blockDim.x + threadIdx.x;
  if (i >= NPTS) return;

  float R00 = viewmat[0], R01 = viewmat[1], R02 = viewmat[2],  t0 = viewmat[3];
  float R10 = viewmat[4], R11 = viewmat[5], R12 = viewmat[6],  t1 = viewmat[7];
  float R20 = viewmat[8], R21 = viewmat[9], R22 = viewmat[10], t2 = viewmat[11];
  float fx = Kmat[0], cx = Kmat[2], fy = Kmat[4], cy = Kmat[5];

  float m0 = means[3 * i], m1 = means[3 * i + 1], m2 = means[3 * i + 2];
  float x = R00 * m0 + R01 * m1 + R02 * m2 + t0;
  float y = R10 * m0 + R11 * m1 + R12 * m2 + t1;
  float z = R20 * m0 + R21 * m1 + R22 * m2 + t2;
  bool valid = (z > ZNEAR) && (z < ZFAR);
  float zc = fmaxf(z, 1e-6f);

  float qw = quats[4 * i], qx = quats[4 * i + 1], qy = quats[4 * i + 2], qz = quats[4 * i + 3];
  float qn = sqrtf(qw * qw + qx * qx + qy * qy + qz * qz);
  qw /= qn; qx /= qn; qy /= qn; qz /= qn;
  float sx = scales[3 * i], sy = scales[3 * i + 1], sz = scales[3 * i + 2];

  // M = quat_to_rotmat(q) with columns scaled by s
  float M00 = (1.f - 2.f * (qy * qy + qz * qz)) * sx;
  float M01 = (2.f * (qx * qy - qw * qz)) * sy;
  float M02 = (2.f * (qx * qz + qw * qy)) * sz;
  float M10 = (2.f * (qx * qy + qw * qz)) * sx;
  float M11 = (1.f - 2.f * (qx * qx + qz * qz)) * sy;
  float M12 = (2.f * (qy * qz - qw * qx)) * sz;
  float M20 = (2.f * (qx * qz - qw * qy)) * sx;
  float M21 = (2.f * (qy * qz + qw * qx)) * sy;
  float M22 = (1.f - 2.f * (qx * qx + qy * qy)) * sz;

  // cov3 = M M^T (symmetric)
  float C00 = M00 * M00 + M01 * M01 + M02 * M02;
  float C01 = M00 * M10 + M01 * M11 + M02 * M12;
  float C02 = M00 * M20 + M01 * M21 + M02 * M22;
  float C11 = M10 * M10 + M11 * M11 + M12 * M12;
  float C12 = M10 * M20 + M11 * M21 + M12 * M22;
  float C22 = M20 * M20 + M21 * M21 + M22 * M22;

  // covc = R * cov3 * R^T
  float B00 = R00 * C00 + R01 * C01 + R02 * C02;
  float B01 = R00 * C01 + R01 * C11 + R02 * C12;
  float B02 = R00 * C02 + R01 * C12 + R02 * C22;
  float B10 = R10 * C00 + R11 * C01 + R12 * C02;
  float B11 = R10 * C01 + R11 * C11 + R12 * C12;
  float B12 = R10 * C02 + R11 * C12 + R12 * C22;
  float B20 = R20 * C00 + R21 * C01 + R22 * C02;
  float B21 = R20 * C01 + R21 * C11 + R22 * C12;
  float B22 = R20 * C02 + R21 * C12 + R22 * C22;

  float V00 = B00 * R00 + B01 * R01 + B02 * R02;
  float V01 = B00 * R10 + B01 * R11 + B02 * R12;
  float V02 = B00 * R20 + B01 * R21 + B02 * R22;
  float V11 = B10 * R10 + B11 * R11 + B12 * R12;
  float V12 = B10 * R20 + B11 * R21 + B12 * R22;
  float V22 = B20 * R20 + B21 * R21 + B22 * R22;

  // J rows: (a0, 0, a2), (0, b1, b2)
  float a0 = fx / zc;
  float a2 = -fx * x / (zc * zc);
  float b1 = fy / zc;
  float b2 = -fy * y / (zc * zc);

  float c00 = a0 * a0 * V00 + 2.f * a0 * a2 * V02 + a2 * a2 * V22;
  float c01 = a0 * b1 * V01 + a0 * b2 * V02 + a2 * b1 * V12 + a2 * b2 * V22;
  float c11 = b1 * b1 * V11 + 2.f * b1 * b2 * V12 + b2 * b2 * V22;

  float a = c00 + EPS2D;
  float b = c01;
  float c = c11 + EPS2D;
  float det = a * c - b * b;
  float cA = c / det;
  float cB = -b / det;
  float cC = a / det;

  float mx = fx * x / zc + cx;
  float my = fy * y / zc + cy;

  float key = valid ? z : __builtin_inff();
  float opac_eff = valid ? opacities[i] : 0.0f;

  un[0 * NPTS + i] = key;
  un[1 * NPTS + i] = mx;
  un[2 * NPTS + i] = my;
  un[3 * NPTS + i] = cA;
  un[4 * NPTS + i] = cB;
  un[5 * NPTS + i] = cC;
  un[6 * NPTS + i] = opac_eff;
  un[7 * NPTS + i] = z;
  un[8 * NPTS + i] = colors[3 * i];
  un[9 * NPTS + i] = colors[3 * i + 1];
  un[10 * NPTS + i] = colors[3 * i + 2];
}

// O(N^2) stable rank-count argsort + scatter into SoA sorted arrays.
__global__ void sortscatter_kernel(const float* __restrict__ un, float* __restrict__ so) {
  __shared__ float keys[NPTS];
  int tid = threadIdx.x;
  for (int j = tid; j < NPTS; j += blockDim.x) keys[j] = un[j];
  __syncthreads();
  int i = blockIdx.x * blockDim.x + tid;
  float ki = keys[i];
  int rank = 0;
  for (int j = 0; j < NPTS; ++j) {
    float kj = keys[j];
    rank += (kj < ki) || (kj == ki && j < i);
  }
#pragma unroll
  for (int a = 0; a < 10; ++a) so[a * NPTS + rank] = un[(a + 1) * NPTS + i];
}

constexpr int SEGS = 8;                    // ordered segments per pixel
constexpr int SEGLEN = NPTS / SEGS;        // 256
constexpr int CH = 128;                    // gaussians staged per seg per round
constexpr int ROUNDS = SEGLEN / CH;        // 2
constexpr int LDS_STRIDE = CH + 4;         // 132: keeps 16B alignment, segs hit distinct banks

__global__ __launch_bounds__(256) void rasterize_kernel(const float* __restrict__ so,
                                                        float* __restrict__ out) {
  __shared__ float lds[10][SEGS][LDS_STRIDE];
  int tid = threadIdx.x;
  int seg = tid & (SEGS - 1);
  int pl = tid >> 3;  // 0..31 pixel within 8x4 tile
  int col = blockIdx.x * 8 + (pl & 7);
  int row = blockIdx.y * 4 + (pl >> 3);
  float px = col + 0.5f, py = row + 0.5f;

  float cr = 0.f, cg = 0.f, cb = 0.f, aa = 0.f, dd = 0.f, T = 1.0f;

  for (int r = 0; r < ROUNDS; ++r) {
    __syncthreads();
    // stage this round's chunk: 10 arrays x SEGS x CH floats, float4 loads
    for (int q = tid; q < 10 * SEGS * (CH / 4); q += 256) {
      int a = q / (SEGS * (CH / 4));
      int rem = q % (SEGS * (CH / 4));
      int s = rem / (CH / 4);
      int k4 = rem % (CH / 4);
      float4 v = *reinterpret_cast<const float4*>(&so[a * NPTS + s * SEGLEN + r * CH + k4 * 4]);
      *reinterpret_cast<float4*>(&lds[a][s][k4 * 4]) = v;
    }
    __syncthreads();

#pragma unroll 4
    for (int k = 0; k < CH; ++k) {
      float gmx = lds[0][seg][k];
      float gmy = lds[1][seg][k];
      float A = lds[2][seg][k];
      float B = lds[3][seg][k];
      float C = lds[4][seg][k];
      float op = lds[5][seg][k];
      float gz = lds[6][seg][k];
      float dx = px - gmx, dy = py - gmy;
      float sigma = 0.5f * (A * dx * dx + C * dy * dy) + B * dx * dy;
      float e = __expf(-sigma);
      float raw = op * e;
      float alpha = fminf(ALPHA_CLIP, raw);
      bool use = (sigma >= 0.0f) && (raw > ALPHA_MIN);
      alpha = use ? alpha : 0.0f;
      float w = alpha * T;
      cr += w * lds[7][seg][k];
      cg += w * lds[8][seg][k];
      cb += w * lds[9][seg][k];
      aa += w;
      dd += w * gz;
      T *= (1.0f - alpha);
    }
  }

  // combine ordered segments across 8 lanes: (C,T) o (C',T') = (C + T*C', T*T')
  for (int d = 1; d < SEGS; d <<= 1) {
    float ocr = __shfl_xor(cr, d);
    float ocg = __shfl_xor(cg, d);
    float ocb = __shfl_xor(cb, d);
    float oaa = __shfl_xor(aa, d);
    float odd = __shfl_xor(dd, d);
    float oT = __shfl_xor(T, d);
    bool upper = (seg & d) != 0;  // self is the later segment
    float fcr = upper ? ocr : cr, scr = upper ? cr : ocr;
    float fcg = upper ? ocg : cg, scg = upper ? cg : ocg;
    float fcb = upper ? ocb : cb, scb = upper ? cb : ocb;
    float faa = upper ? oaa : aa, saa = upper ? aa : oaa;
    float fdd = upper ? odd : dd, sdd = upper ? dd : odd;
    float fT = upper ? oT : T, sT = upper ? T : oT;
    cr = fcr + fT * scr;
    cg = fcg + fT * scg;
    cb = fcb + fT * scb;
    aa = faa + fT * saa;
    dd = fdd + fT * sdd;
    T = fT * sT;
  }

  if (seg == 0) {
    int pix = row * HW + col;
    out[pix * 3 + 0] = cr;
    out[pix * 3 + 1] = cg;
    out[pix * 3 + 2] = cb;
    out[HW * HW * 3 + pix] = aa;
    out[HW * HW * 4 + pix] = dd / fmaxf(aa, 1e-10f);
  }
}

extern "C" void kernel_launch(void* const* d_in, const int* in_sizes, int n_in,
                              void* d_out, int out_size, void* d_ws, size_t ws_size,
                              hipStream_t stream) {
  const float* means = (const float*)d_in[0];
  const float* quats = (const float*)d_in[1];
  const float* scales = (const float*)d_in[2];
  const float* opacities = (const float*)d_in[3];
  const float* colors = (const float*)d_in[4];
  const float* viewmats = (const float*)d_in[5];
  const float* Ks = (const float*)d_in[6];
  float* out = (float*)d_out;
  float* ws = (float*)d_ws;

  float* un = ws;                 // 11 * NPTS
  float* so = ws + 11 * NPTS;     // 10 * NPTS

  preprocess_kernel<<<NPTS / 256, 256, 0, stream>>>(means, quats, scales, opacities, colors,
                                                    viewmats, Ks, un);
  sortscatter_kernel<<<NPTS / 256, 256, 0, stream>>>(un, so);
  dim3 grid(HW / 8, HW / 4);
  rasterize_kernel<<<grid, 256, 0, stream>>>(so, out);
}

// Round 2
// 49.486 us; speedup vs baseline: 1.8911x; 1.8911x over previous
//
#include <hip/hip_runtime.h>
#include <math.h>

#define HW 128
#define NPTS 2048

constexpr float ZNEAR = 0.01f, ZFAR = 100.0f;
constexpr float EPS2D = 0.3f;
constexpr float ALPHA_CLIP = 0.999f;
constexpr float ALPHA_MIN = 1.0f / 255.0f;

// ws layout (floats):
//   un: 11 arrays * NPTS : [key, mx, my, cA, cB, cC, opac, z, r, g, b]
//   so: 10 arrays * NPTS : [mx, my, cA, cB, cC, opac, z, r, g, b]

__global__ void preprocess_kernel(const float* __restrict__ means,
                                  const float* __restrict__ quats,
                                  const float* __restrict__ scales,
                                  const float* __restrict__ opacities,
                                  const float* __restrict__ colors,
                                  const float* __restrict__ viewmat,
                                  const float* __restrict__ Kmat,
                                  float* __restrict__ un) {
  int i = blockIdx.x * blockDim.x + threadIdx.x;
  if (i >= NPTS) return;

  float R00 = viewmat[0], R01 = viewmat[1], R02 = viewmat[2],  t0 = viewmat[3];
  float R10 = viewmat[4], R11 = viewmat[5], R12 = viewmat[6],  t1 = viewmat[7];
  float R20 = viewmat[8], R21 = viewmat[9], R22 = viewmat[10], t2 = viewmat[11];
  float fx = Kmat[0], cx = Kmat[2], fy = Kmat[4], cy = Kmat[5];

  float m0 = means[3 * i], m1 = means[3 * i + 1], m2 = means[3 * i + 2];
  float x = R00 * m0 + R01 * m1 + R02 * m2 + t0;
  float y = R10 * m0 + R11 * m1 + R12 * m2 + t1;
  float z = R20 * m0 + R21 * m1 + R22 * m2 + t2;
  bool valid = (z > ZNEAR) && (z < ZFAR);
  float zc = fmaxf(z, 1e-6f);

  float qw = quats[4 * i], qx = quats[4 * i + 1], qy = quats[4 * i + 2], qz = quats[4 * i + 3];
  float qn = sqrtf(qw * qw + qx * qx + qy * qy + qz * qz);
  qw /= qn; qx /= qn; qy /= qn; qz /= qn;
  float sx = scales[3 * i], sy = scales[3 * i + 1], sz = scales[3 * i + 2];

  // M = quat_to_rotmat(q) with columns scaled by s
  float M00 = (1.f - 2.f * (qy * qy + qz * qz)) * sx;
  float M01 = (2.f * (qx * qy - qw * qz)) * sy;
  float M02 = (2.f * (qx * qz + qw * qy)) * sz;
  float M10 = (2.f * (qx * qy + qw * qz)) * sx;
  float M11 = (1.f - 2.f * (qx * qx + qz * qz)) * sy;
  float M12 = (2.f * (qy * qz - qw * qx)) * sz;
  float M20 = (2.f * (qx * qz - qw * qy)) * sx;
  float M21 = (2.f * (qy * qz + qw * qx)) * sy;
  float M22 = (1.f - 2.f * (qx * qx + qy * qy)) * sz;

  // cov3 = M M^T (symmetric)
  float C00 = M00 * M00 + M01 * M01 + M02 * M02;
  float C01 = M00 * M10 + M01 * M11 + M02 * M12;
  float C02 = M00 * M20 + M01 * M21 + M02 * M22;
  float C11 = M10 * M10 + M11 * M11 + M12 * M12;
  float C12 = M10 * M20 + M11 * M21 + M12 * M22;
  float C22 = M20 * M20 + M21 * M21 + M22 * M22;

  // covc = R * cov3 * R^T
  float B00 = R00 * C00 + R01 * C01 + R02 * C02;
  float B01 = R00 * C01 + R01 * C11 + R02 * C12;
  float B02 = R00 * C02 + R01 * C12 + R02 * C22;
  float B10 = R10 * C00 + R11 * C01 + R12 * C02;
  float B11 = R10 * C01 + R11 * C11 + R12 * C12;
  float B12 = R10 * C02 + R11 * C12 + R12 * C22;
  float B20 = R20 * C00 + R21 * C01 + R22 * C02;
  float B21 = R20 * C01 + R21 * C11 + R22 * C12;
  float B22 = R20 * C02 + R21 * C12 + R22 * C22;

  float V00 = B00 * R00 + B01 * R01 + B02 * R02;
  float V01 = B00 * R10 + B01 * R11 + B02 * R12;
  float V02 = B00 * R20 + B01 * R21 + B02 * R22;
  float V11 = B10 * R10 + B11 * R11 + B12 * R12;
  float V12 = B10 * R20 + B11 * R21 + B12 * R22;
  float V22 = B20 * R20 + B21 * R21 + B22 * R22;

  // J rows: (a0, 0, a2), (0, b1, b2)
  float a0 = fx / zc;
  float a2 = -fx * x / (zc * zc);
  float b1 = fy / zc;
  float b2 = -fy * y / (zc * zc);

  float c00 = a0 * a0 * V00 + 2.f * a0 * a2 * V02 + a2 * a2 * V22;
  float c01 = a0 * b1 * V01 + a0 * b2 * V02 + a2 * b1 * V12 + a2 * b2 * V22;
  float c11 = b1 * b1 * V11 + 2.f * b1 * b2 * V12 + b2 * b2 * V22;

  float a = c00 + EPS2D;
  float b = c01;
  float c = c11 + EPS2D;
  float det = a * c - b * b;
  float cA = c / det;
  float cB = -b / det;
  float cC = a / det;

  float mx = fx * x / zc + cx;
  float my = fy * y / zc + cy;

  float key = valid ? z : __builtin_inff();
  float opac_eff = valid ? opacities[i] : 0.0f;

  un[0 * NPTS + i] = key;
  un[1 * NPTS + i] = mx;
  un[2 * NPTS + i] = my;
  un[3 * NPTS + i] = cA;
  un[4 * NPTS + i] = cB;
  un[5 * NPTS + i] = cC;
  un[6 * NPTS + i] = opac_eff;
  un[7 * NPTS + i] = z;
  un[8 * NPTS + i] = colors[3 * i];
  un[9 * NPTS + i] = colors[3 * i + 1];
  un[10 * NPTS + i] = colors[3 * i + 2];
}

// O(N^2) stable rank-count argsort + scatter. 8 threads cooperate per Gaussian:
// each scans 1/8 of the keys (interleaved float4s -> conflict-free LDS), then a
// 3-step shuffle reduce combines partial ranks. Identical comparison semantics
// to the serial version => identical ranks.
constexpr int IPB = 32;  // Gaussians per block
__global__ __launch_bounds__(256) void sortscatter_kernel(const float* __restrict__ un,
                                                          float* __restrict__ so) {
  __shared__ float keys[NPTS];
  int tid = threadIdx.x;
  for (int j = tid * 4; j < NPTS; j += 256 * 4) {
    *reinterpret_cast<float4*>(&keys[j]) = *reinterpret_cast<const float4*>(&un[j]);
  }
  __syncthreads();

  int li = tid >> 3;   // 0..31 Gaussian within block
  int sub = tid & 7;   // 0..7 key-slice
  int i = blockIdx.x * IPB + li;
  float ki = keys[i];
  int rank = 0;
  // sub-lane s handles float4 indices s, s+8, s+16, ... (consecutive across subs
  // for fixed m -> 8 float4 = 128B = all 32 banks, conflict-free; broadcast across li)
  for (int m = 0; m < NPTS / 4 / 8; ++m) {
    int j4 = m * 8 + sub;
    int j = j4 * 4;
    float4 k4 = *reinterpret_cast<const float4*>(&keys[j]);
    rank += (k4.x < ki) || (k4.x == ki && (j + 0) < i);
    rank += (k4.y < ki) || (k4.y == ki && (j + 1) < i);
    rank += (k4.z < ki) || (k4.z == ki && (j + 2) < i);
    rank += (k4.w < ki) || (k4.w == ki && (j + 3) < i);
  }
  rank += __shfl_xor(rank, 1);
  rank += __shfl_xor(rank, 2);
  rank += __shfl_xor(rank, 4);

  if (sub == 0) {
#pragma unroll
    for (int a = 0; a < 10; ++a) so[a * NPTS + rank] = un[(a + 1) * NPTS + i];
  }
}

constexpr int SEGS = 8;                    // ordered segments per pixel
constexpr int SEGLEN = NPTS / SEGS;        // 256
constexpr int CH = 128;                    // gaussians staged per seg per round
constexpr int ROUNDS = SEGLEN / CH;        // 2
constexpr int LDS_STRIDE = CH + 4;         // 132: keeps 16B alignment, segs hit distinct banks

__global__ __launch_bounds__(256) void rasterize_kernel(const float* __restrict__ so,
                                                        float* __restrict__ out) {
  __shared__ float lds[10][SEGS][LDS_STRIDE];
  int tid = threadIdx.x;
  int seg = tid & (SEGS - 1);
  int pl = tid >> 3;  // 0..31 pixel within 8x4 tile
  int col = blockIdx.x * 8 + (pl & 7);
  int row = blockIdx.y * 4 + (pl >> 3);
  float px = col + 0.5f, py = row + 0.5f;

  float cr = 0.f, cg = 0.f, cb = 0.f, aa = 0.f, dd = 0.f, T = 1.0f;

  for (int r = 0; r < ROUNDS; ++r) {
    __syncthreads();
    // stage this round's chunk: 10 arrays x SEGS x CH floats, float4 loads
    for (int q = tid; q < 10 * SEGS * (CH / 4); q += 256) {
      int a = q / (SEGS * (CH / 4));
      int rem = q % (SEGS * (CH / 4));
      int s = rem / (CH / 4);
      int k4 = rem % (CH / 4);
      float4 v = *reinterpret_cast<const float4*>(&so[a * NPTS + s * SEGLEN + r * CH + k4 * 4]);
      *reinterpret_cast<float4*>(&lds[a][s][k4 * 4]) = v;
    }
    __syncthreads();

#pragma unroll 4
    for (int k = 0; k < CH; ++k) {
      float gmx = lds[0][seg][k];
      float gmy = lds[1][seg][k];
      float A = lds[2][seg][k];
      float B = lds[3][seg][k];
      float C = lds[4][seg][k];
      float op = lds[5][seg][k];
      float gz = lds[6][seg][k];
      float dx = px - gmx, dy = py - gmy;
      float sigma = 0.5f * (A * dx * dx + C * dy * dy) + B * dx * dy;
      float e = __expf(-sigma);
      float raw = op * e;
      float alpha = fminf(ALPHA_CLIP, raw);
      bool use = (sigma >= 0.0f) && (raw > ALPHA_MIN);
      alpha = use ? alpha : 0.0f;
      float w = alpha * T;
      cr += w * lds[7][seg][k];
      cg += w * lds[8][seg][k];
      cb += w * lds[9][seg][k];
      aa += w;
      dd += w * gz;
      T *= (1.0f - alpha);
    }
  }

  // combine ordered segments across 8 lanes: (C,T) o (C',T') = (C + T*C', T*T')
  for (int d = 1; d < SEGS; d <<= 1) {
    float ocr = __shfl_xor(cr, d);
    float ocg = __shfl_xor(cg, d);
    float ocb = __shfl_xor(cb, d);
    float oaa = __shfl_xor(aa, d);
    float odd = __shfl_xor(dd, d);
    float oT = __shfl_xor(T, d);
    bool upper = (seg & d) != 0;  // self is the later segment
    float fcr = upper ? ocr : cr, scr = upper ? cr : ocr;
    float fcg = upper ? ocg : cg, scg = upper ? cg : ocg;
    float fcb = upper ? ocb : cb, scb = upper ? cb : ocb;
    float faa = upper ? oaa : aa, saa = upper ? aa : oaa;
    float fdd = upper ? odd : dd, sdd = upper ? dd : odd;
    float fT = upper ? oT : T, sT = upper ? T : oT;
    cr = fcr + fT * scr;
    cg = fcg + fT * scg;
    cb = fcb + fT * scb;
    aa = faa + fT * saa;
    dd = fdd + fT * sdd;
    T = fT * sT;
  }

  if (seg == 0) {
    int pix = row * HW + col;
    out[pix * 3 + 0] = cr;
    out[pix * 3 + 1] = cg;
    out[pix * 3 + 2] = cb;
    out[HW * HW * 3 + pix] = aa;
    out[HW * HW * 4 + pix] = dd / fmaxf(aa, 1e-10f);
  }
}

extern "C" void kernel_launch(void* const* d_in, const int* in_sizes, int n_in,
                              void* d_out, int out_size, void* d_ws, size_t ws_size,
                              hipStream_t stream) {
  const float* means = (const float*)d_in[0];
  const float* quats = (const float*)d_in[1];
  const float* scales = (const float*)d_in[2];
  const float* opacities = (const float*)d_in[3];
  const float* colors = (const float*)d_in[4];
  const float* viewmats = (const float*)d_in[5];
  const float* Ks = (const float*)d_in[6];
  float* out = (float*)d_out;
  float* ws = (float*)d_ws;

  float* un = ws;                 // 11 * NPTS
  float* so = ws + 11 * NPTS;     // 10 * NPTS

  preprocess_kernel<<<NPTS / 256, 256, 0, stream>>>(means, quats, scales, opacities, colors,
                                                    viewmats, Ks, un);
  sortscatter_kernel<<<NPTS / IPB, 256, 0, stream>>>(un, so);
  dim3 grid(HW / 8, HW / 4);
  rasterize_kernel<<<grid, 256, 0, stream>>>(so, out);
}

// Round 3
// 32.431 us; speedup vs baseline: 2.8857x; 1.5259x over previous
//
#include <hip/hip_runtime.h>
#include <math.h>

#define HW 128
#define NPTS 2048

constexpr float ZNEAR = 0.01f, ZFAR = 100.0f;
constexpr float EPS2D = 0.3f;
constexpr float ALPHA_CLIP = 0.999f;
constexpr float ALPHA_MIN = 1.0f / 255.0f;

// ws layout (floats):
//   un: 13 arrays * NPTS : [key, mx, my, cA, cB, cC, opac, z, r, g, b, rx, ry]
//   so: 12 arrays * NPTS : [mx, my, cA, cB, cC, opac, z, r, g, b, rx, ry]

__global__ void preprocess_kernel(const float* __restrict__ means,
                                  const float* __restrict__ quats,
                                  const float* __restrict__ scales,
                                  const float* __restrict__ opacities,
                                  const float* __restrict__ colors,
                                  const float* __restrict__ viewmat,
                                  const float* __restrict__ Kmat,
                                  float* __restrict__ un) {
  int i = blockIdx.x * blockDim.x + threadIdx.x;
  if (i >= NPTS) return;

  float R00 = viewmat[0], R01 = viewmat[1], R02 = viewmat[2],  t0 = viewmat[3];
  float R10 = viewmat[4], R11 = viewmat[5], R12 = viewmat[6],  t1 = viewmat[7];
  float R20 = viewmat[8], R21 = viewmat[9], R22 = viewmat[10], t2 = viewmat[11];
  float fx = Kmat[0], cx = Kmat[2], fy = Kmat[4], cy = Kmat[5];

  float m0 = means[3 * i], m1 = means[3 * i + 1], m2 = means[3 * i + 2];
  float x = R00 * m0 + R01 * m1 + R02 * m2 + t0;
  float y = R10 * m0 + R11 * m1 + R12 * m2 + t1;
  float z = R20 * m0 + R21 * m1 + R22 * m2 + t2;
  bool valid = (z > ZNEAR) && (z < ZFAR);
  float zc = fmaxf(z, 1e-6f);

  float qw = quats[4 * i], qx = quats[4 * i + 1], qy = quats[4 * i + 2], qz = quats[4 * i + 3];
  float qn = sqrtf(qw * qw + qx * qx + qy * qy + qz * qz);
  qw /= qn; qx /= qn; qy /= qn; qz /= qn;
  float sx = scales[3 * i], sy = scales[3 * i + 1], sz = scales[3 * i + 2];

  // M = quat_to_rotmat(q) with columns scaled by s
  float M00 = (1.f - 2.f * (qy * qy + qz * qz)) * sx;
  float M01 = (2.f * (qx * qy - qw * qz)) * sy;
  float M02 = (2.f * (qx * qz + qw * qy)) * sz;
  float M10 = (2.f * (qx * qy + qw * qz)) * sx;
  float M11 = (1.f - 2.f * (qx * qx + qz * qz)) * sy;
  float M12 = (2.f * (qy * qz - qw * qx)) * sz;
  float M20 = (2.f * (qx * qz - qw * qy)) * sx;
  float M21 = (2.f * (qy * qz + qw * qx)) * sy;
  float M22 = (1.f - 2.f * (qx * qx + qy * qy)) * sz;

  // cov3 = M M^T (symmetric)
  float C00 = M00 * M00 + M01 * M01 + M02 * M02;
  float C01 = M00 * M10 + M01 * M11 + M02 * M12;
  float C02 = M00 * M20 + M01 * M21 + M02 * M22;
  float C11 = M10 * M10 + M11 * M11 + M12 * M12;
  float C12 = M10 * M20 + M11 * M21 + M12 * M22;
  float C22 = M20 * M20 + M21 * M21 + M22 * M22;

  // covc = R * cov3 * R^T
  float B00 = R00 * C00 + R01 * C01 + R02 * C02;
  float B01 = R00 * C01 + R01 * C11 + R02 * C12;
  float B02 = R00 * C02 + R01 * C12 + R02 * C22;
  float B10 = R10 * C00 + R11 * C01 + R12 * C02;
  float B11 = R10 * C01 + R11 * C11 + R12 * C12;
  float B12 = R10 * C02 + R11 * C12 + R12 * C22;
  float B20 = R20 * C00 + R21 * C01 + R22 * C02;
  float B21 = R20 * C01 + R21 * C11 + R22 * C12;
  float B22 = R20 * C02 + R21 * C12 + R22 * C22;

  float V00 = B00 * R00 + B01 * R01 + B02 * R02;
  float V01 = B00 * R10 + B01 * R11 + B02 * R12;
  float V02 = B00 * R20 + B01 * R21 + B02 * R22;
  float V11 = B10 * R10 + B11 * R11 + B12 * R12;
  float V12 = B10 * R20 + B11 * R21 + B12 * R22;
  float V22 = B20 * R20 + B21 * R21 + B22 * R22;

  // J rows: (a0, 0, a2), (0, b1, b2)
  float a0 = fx / zc;
  float a2 = -fx * x / (zc * zc);
  float b1 = fy / zc;
  float b2 = -fy * y / (zc * zc);

  float c00 = a0 * a0 * V00 + 2.f * a0 * a2 * V02 + a2 * a2 * V22;
  float c01 = a0 * b1 * V01 + a0 * b2 * V02 + a2 * b1 * V12 + a2 * b2 * V22;
  float c11 = b1 * b1 * V11 + 2.f * b1 * b2 * V12 + b2 * b2 * V22;

  float a = c00 + EPS2D;
  float b = c01;
  float c = c11 + EPS2D;
  float det = a * c - b * b;
  float cA = c / det;
  float cB = -b / det;
  float cC = a / det;

  float mx = fx * x / zc + cx;
  float my = fy * y / zc + cy;

  float key = valid ? z : __builtin_inff();
  float opac_eff = valid ? opacities[i] : 0.0f;

  // Exact cull radius: alpha contribution is 0 wherever sigma >= tau = ln(255*opac).
  // Ellipse {sigma <= tau} has max |dx| = sqrt(2 tau a), max |dy| = sqrt(2 tau c)
  // (a, c are the pre-inversion 2D cov diag + eps). opac=0 -> tau=-inf -> NaN -> culled.
  float tau = logf(255.0f * opac_eff);
  float rx = sqrtf(2.0f * tau * a);
  float ry = sqrtf(2.0f * tau * c);

  un[0 * NPTS + i] = key;
  un[1 * NPTS + i] = mx;
  un[2 * NPTS + i] = my;
  un[3 * NPTS + i] = cA;
  un[4 * NPTS + i] = cB;
  un[5 * NPTS + i] = cC;
  un[6 * NPTS + i] = opac_eff;
  un[7 * NPTS + i] = z;
  un[8 * NPTS + i] = colors[3 * i];
  un[9 * NPTS + i] = colors[3 * i + 1];
  un[10 * NPTS + i] = colors[3 * i + 2];
  un[11 * NPTS + i] = rx;
  un[12 * NPTS + i] = ry;
}

// O(N^2) stable rank-count argsort + scatter. 8 threads cooperate per Gaussian.
constexpr int IPB = 32;  // Gaussians per block
__global__ __launch_bounds__(256) void sortscatter_kernel(const float* __restrict__ un,
                                                          float* __restrict__ so) {
  __shared__ float keys[NPTS];
  int tid = threadIdx.x;
  for (int j = tid * 4; j < NPTS; j += 256 * 4) {
    *reinterpret_cast<float4*>(&keys[j]) = *reinterpret_cast<const float4*>(&un[j]);
  }
  __syncthreads();

  int li = tid >> 3;   // 0..31 Gaussian within block
  int sub = tid & 7;   // 0..7 key-slice
  int i = blockIdx.x * IPB + li;
  float ki = keys[i];
  int rank = 0;
  for (int m = 0; m < NPTS / 4 / 8; ++m) {
    int j4 = m * 8 + sub;
    int j = j4 * 4;
    float4 k4 = *reinterpret_cast<const float4*>(&keys[j]);
    rank += (k4.x < ki) || (k4.x == ki && (j + 0) < i);
    rank += (k4.y < ki) || (k4.y == ki && (j + 1) < i);
    rank += (k4.z < ki) || (k4.z == ki && (j + 2) < i);
    rank += (k4.w < ki) || (k4.w == ki && (j + 3) < i);
  }
  rank += __shfl_xor(rank, 1);
  rank += __shfl_xor(rank, 2);
  rank += __shfl_xor(rank, 4);

  if (sub == 0) {
#pragma unroll
    for (int a = 0; a < 12; ++a) so[a * NPTS + rank] = un[(a + 1) * NPTS + i];
  }
}

// Tile-based rasterization: one block per 16x16 tile.
// Phase 1: stable stream-compaction of the depth-sorted list against the tile's
//          exact contribution bounds (order preserved -> exact sequential compositing).
// Phase 2: stage survivors into LDS SoA chunks, composite thread-per-pixel.
constexpr int TSX = 16, TSY = 16;
constexpr int C2 = 128;  // composite chunk size

__global__ __launch_bounds__(256) void rasterize_kernel(const float* __restrict__ so,
                                                        float* __restrict__ out) {
  __shared__ unsigned short list[NPTS];
  __shared__ float stage[C2][12];  // rows 48B -> float4-aligned; [mx,my,cA,cB,cC,op,z,r,g,b,-,-]
  __shared__ int wcnt[4];
  __shared__ int sLen;

  int tid = threadIdx.x;
  int tileX = blockIdx.x, tileY = blockIdx.y;
  const float SLACK = 0.5f;
  float x0 = tileX * TSX + 0.5f - SLACK;
  float x1 = tileX * TSX + (TSX - 1) + 0.5f + SLACK;
  float y0 = tileY * TSY + 0.5f - SLACK;
  float y1 = tileY * TSY + (TSY - 1) + 0.5f + SLACK;

  if (tid == 0) sLen = 0;
  __syncthreads();

  const float* __restrict__ mxA = so + 0 * NPTS;
  const float* __restrict__ myA = so + 1 * NPTS;
  const float* __restrict__ rxA = so + 10 * NPTS;
  const float* __restrict__ ryA = so + 11 * NPTS;

  int wave = tid >> 6, lane = tid & 63;
  for (int base = 0; base < NPTS; base += 256) {
    int g = base + tid;
    float mx = mxA[g], my = myA[g], rx = rxA[g], ry = ryA[g];
    // NaN rx/ry (culled gaussians) -> comparisons false -> dropped
    bool keep = (mx + rx >= x0) && (mx - rx <= x1) && (my + ry >= y0) && (my - ry <= y1);
    unsigned long long m = __ballot(keep);
    if (lane == 0) wcnt[wave] = __popcll(m);
    __syncthreads();
    int off = sLen;
    for (int w = 0; w < wave; ++w) off += wcnt[w];
    off += __popcll(m & ((1ull << lane) - 1ull));
    if (keep) list[off] = (unsigned short)g;
    __syncthreads();
    if (tid == 0) sLen += wcnt[0] + wcnt[1] + wcnt[2] + wcnt[3];
    __syncthreads();
  }
  int L = sLen;

  int pxi = tid & 15, pyi = tid >> 4;
  float pxf = tileX * TSX + pxi + 0.5f;
  float pyf = tileY * TSY + pyi + 0.5f;

  float cr = 0.f, cg = 0.f, cbv = 0.f, aa = 0.f, dd = 0.f, T = 1.0f;

  for (int cbase = 0; cbase < L; cbase += C2) {
    int n = min(C2, L - cbase);
    __syncthreads();  // protect stage reuse
    for (int q = tid; q < n * 10; q += 256) {
      int j = q / 10, a2 = q % 10;
      stage[j][a2] = so[a2 * NPTS + (int)list[cbase + j]];
    }
    __syncthreads();

    for (int j = 0; j < n; ++j) {
      float4 v0 = *reinterpret_cast<const float4*>(&stage[j][0]);  // mx,my,cA,cB
      float4 v1 = *reinterpret_cast<const float4*>(&stage[j][4]);  // cC,op,z,r
      float2 v2 = *reinterpret_cast<const float2*>(&stage[j][8]);  // g,b
      float dx = pxf - v0.x, dy = pyf - v0.y;
      float sigma = 0.5f * (v0.z * dx * dx + v1.x * dy * dy) + v0.w * dx * dy;
      float e = __expf(-sigma);
      float raw = v1.y * e;
      float alpha = fminf(ALPHA_CLIP, raw);
      bool use = (sigma >= 0.0f) && (raw > ALPHA_MIN);
      alpha = use ? alpha : 0.0f;
      float w = alpha * T;
      cr += w * v1.w;
      cg += w * v2.x;
      cbv += w * v2.y;
      aa += w;
      dd += w * v1.z;
      T *= (1.0f - alpha);
    }
  }

  int pix = (tileY * TSY + pyi) * HW + (tileX * TSX + pxi);
  out[pix * 3 + 0] = cr;
  out[pix * 3 + 1] = cg;
  out[pix * 3 + 2] = cbv;
  out[HW * HW * 3 + pix] = aa;
  out[HW * HW * 4 + pix] = dd / fmaxf(aa, 1e-10f);
}

extern "C" void kernel_launch(void* const* d_in, const int* in_sizes, int n_in,
                              void* d_out, int out_size, void* d_ws, size_t ws_size,
                              hipStream_t stream) {
  const float* means = (const float*)d_in[0];
  const float* quats = (const float*)d_in[1];
  const float* scales = (const float*)d_in[2];
  const float* opacities = (const float*)d_in[3];
  const float* colors = (const float*)d_in[4];
  const float* viewmats = (const float*)d_in[5];
  const float* Ks = (const float*)d_in[6];
  float* out = (float*)d_out;
  float* ws = (float*)d_ws;

  float* un = ws;                 // 13 * NPTS
  float* so = ws + 13 * NPTS;     // 12 * NPTS

  preprocess_kernel<<<NPTS / 256, 256, 0, stream>>>(means, quats, scales, opacities, colors,
                                                    viewmats, Ks, un);
  sortscatter_kernel<<<NPTS / IPB, 256, 0, stream>>>(un, so);
  dim3 grid(HW / TSX, HW / TSY);
  rasterize_kernel<<<grid, 256, 0, stream>>>(so, out);
}

// Round 4
// 24.764 us; speedup vs baseline: 3.7791x; 1.3096x over previous
//
#include <hip/hip_runtime.h>
#include <math.h>

#define HW 128
#define NPTS 2048

constexpr float ZNEAR = 0.01f, ZFAR = 100.0f;
constexpr float EPS2D = 0.3f;
constexpr float ALPHA_CLIP = 0.999f;
constexpr float ALPHA_MIN = 1.0f / 255.0f;

// ws layout (floats):
//   key    @ 0      : NPTS
//   pb     @ 2048   : NPTS float4 (mx,my,rx,ry)          unsorted
//   pa     @ 10240  : NPTS x 3 float4 (attr AoS)         unsorted
//   attr   @ 34816  : NPTS x 3 float4 (attr AoS)         depth-sorted
//   bounds @ 59392  : NPTS float4 (mx,my,rx,ry)          depth-sorted

__global__ __launch_bounds__(64) void preprocess_kernel(const float* __restrict__ means,
                                                        const float* __restrict__ quats,
                                                        const float* __restrict__ scales,
                                                        const float* __restrict__ opacities,
                                                        const float* __restrict__ colors,
                                                        const float* __restrict__ viewmat,
                                                        const float* __restrict__ Kmat,
                                                        float* __restrict__ key,
                                                        float4* __restrict__ pb,
                                                        float4* __restrict__ pa) {
  int i = blockIdx.x * 64 + threadIdx.x;
  if (i >= NPTS) return;

  float R00 = viewmat[0], R01 = viewmat[1], R02 = viewmat[2],  t0 = viewmat[3];
  float R10 = viewmat[4], R11 = viewmat[5], R12 = viewmat[6],  t1 = viewmat[7];
  float R20 = viewmat[8], R21 = viewmat[9], R22 = viewmat[10], t2 = viewmat[11];
  float fx = Kmat[0], cx = Kmat[2], fy = Kmat[4], cy = Kmat[5];

  float m0 = means[3 * i], m1 = means[3 * i + 1], m2 = means[3 * i + 2];
  float x = R00 * m0 + R01 * m1 + R02 * m2 + t0;
  float y = R10 * m0 + R11 * m1 + R12 * m2 + t1;
  float z = R20 * m0 + R21 * m1 + R22 * m2 + t2;
  bool valid = (z > ZNEAR) && (z < ZFAR);
  float zc = fmaxf(z, 1e-6f);

  float qw = quats[4 * i], qx = quats[4 * i + 1], qy = quats[4 * i + 2], qz = quats[4 * i + 3];
  float qn = sqrtf(qw * qw + qx * qx + qy * qy + qz * qz);
  qw /= qn; qx /= qn; qy /= qn; qz /= qn;
  float sx = scales[3 * i], sy = scales[3 * i + 1], sz = scales[3 * i + 2];

  float M00 = (1.f - 2.f * (qy * qy + qz * qz)) * sx;
  float M01 = (2.f * (qx * qy - qw * qz)) * sy;
  float M02 = (2.f * (qx * qz + qw * qy)) * sz;
  float M10 = (2.f * (qx * qy + qw * qz)) * sx;
  float M11 = (1.f - 2.f * (qx * qx + qz * qz)) * sy;
  float M12 = (2.f * (qy * qz - qw * qx)) * sz;
  float M20 = (2.f * (qx * qz - qw * qy)) * sx;
  float M21 = (2.f * (qy * qz + qw * qx)) * sy;
  float M22 = (1.f - 2.f * (qx * qx + qy * qy)) * sz;

  float C00 = M00 * M00 + M01 * M01 + M02 * M02;
  float C01 = M00 * M10 + M01 * M11 + M02 * M12;
  float C02 = M00 * M20 + M01 * M21 + M02 * M22;
  float C11 = M10 * M10 + M11 * M11 + M12 * M12;
  float C12 = M10 * M20 + M11 * M21 + M12 * M22;
  float C22 = M20 * M20 + M21 * M21 + M22 * M22;

  float B00 = R00 * C00 + R01 * C01 + R02 * C02;
  float B01 = R00 * C01 + R01 * C11 + R02 * C12;
  float B02 = R00 * C02 + R01 * C12 + R02 * C22;
  float B10 = R10 * C00 + R11 * C01 + R12 * C02;
  float B11 = R10 * C01 + R11 * C11 + R12 * C12;
  float B12 = R10 * C02 + R11 * C12 + R12 * C22;
  float B20 = R20 * C00 + R21 * C01 + R22 * C02;
  float B21 = R20 * C01 + R21 * C11 + R22 * C12;
  float B22 = R20 * C02 + R21 * C12 + R22 * C22;

  float V00 = B00 * R00 + B01 * R01 + B02 * R02;
  float V01 = B00 * R10 + B01 * R11 + B02 * R12;
  float V02 = B00 * R20 + B01 * R21 + B02 * R22;
  float V11 = B10 * R10 + B11 * R11 + B12 * R12;
  float V12 = B10 * R20 + B11 * R21 + B12 * R22;
  float V22 = B20 * R20 + B21 * R21 + B22 * R22;

  float a0 = fx / zc;
  float a2 = -fx * x / (zc * zc);
  float b1 = fy / zc;
  float b2 = -fy * y / (zc * zc);

  float c00 = a0 * a0 * V00 + 2.f * a0 * a2 * V02 + a2 * a2 * V22;
  float c01 = a0 * b1 * V01 + a0 * b2 * V02 + a2 * b1 * V12 + a2 * b2 * V22;
  float c11 = b1 * b1 * V11 + 2.f * b1 * b2 * V12 + b2 * b2 * V22;

  float a = c00 + EPS2D;
  float b = c01;
  float c = c11 + EPS2D;
  float det = a * c - b * b;
  float cA = c / det;
  float cB = -b / det;
  float cC = a / det;

  float mx = fx * x / zc + cx;
  float my = fy * y / zc + cy;

  float opac_eff = valid ? opacities[i] : 0.0f;

  // Exact cull radius: contribution is 0 wherever sigma >= tau = ln(255*opac).
  // Ellipse {sigma <= tau}: max |dx| = sqrt(2 tau a), max |dy| = sqrt(2 tau c).
  // opac_eff<=1/255 -> tau<=0 -> NaN/0 radius -> culled (exactly correct).
  float tau = logf(255.0f * opac_eff);
  float rxv = sqrtf(2.0f * tau * a);
  float ryv = sqrtf(2.0f * tau * c);

  key[i] = valid ? z : __builtin_inff();
  pb[i] = make_float4(mx, my, rxv, ryv);
  pa[3 * i + 0] = make_float4(mx, my, cA, cB);
  pa[3 * i + 1] = make_float4(cC, opac_eff, z, colors[3 * i]);
  pa[3 * i + 2] = make_float4(colors[3 * i + 1], colors[3 * i + 2], 0.f, 0.f);
}

// O(N^2) stable rank-count argsort + AoS scatter. 8 threads per Gaussian.
__global__ __launch_bounds__(256) void sortscatter_kernel(const float* __restrict__ key,
                                                          const float4* __restrict__ pb,
                                                          const float4* __restrict__ pa,
                                                          float4* __restrict__ bounds,
                                                          float4* __restrict__ attr) {
  __shared__ float keys[NPTS];
  int tid = threadIdx.x;
  for (int j = tid * 4; j < NPTS; j += 256 * 4) {
    *reinterpret_cast<float4*>(&keys[j]) = *reinterpret_cast<const float4*>(&key[j]);
  }
  __syncthreads();

  int li = tid >> 3;   // Gaussian within block
  int sub = tid & 7;   // key-slice
  int i = blockIdx.x * 32 + li;
  float ki = keys[i];
  int rank = 0;
  for (int m = 0; m < NPTS / 32; ++m) {
    int j = (m * 8 + sub) * 4;
    float4 k4 = *reinterpret_cast<const float4*>(&keys[j]);
    rank += (k4.x < ki) || (k4.x == ki && (j + 0) < i);
    rank += (k4.y < ki) || (k4.y == ki && (j + 1) < i);
    rank += (k4.z < ki) || (k4.z == ki && (j + 2) < i);
    rank += (k4.w < ki) || (k4.w == ki && (j + 3) < i);
  }
  rank += __shfl_xor(rank, 1);
  rank += __shfl_xor(rank, 2);
  rank += __shfl_xor(rank, 4);  // butterfly: all 8 sub-lanes hold the total

  if (sub < 3) attr[rank * 3 + sub] = pa[i * 3 + sub];
  else if (sub == 3) bounds[rank] = pb[i];
}

// One block per 8x8 tile (grid 16x16), 4 waves. Wave w stream-compacts sorted
// depth-quarter [512w, 512w+512) with intra-wave ballots (no block barriers),
// then composites its own list for all 64 pixels (lane=pixel), staging 16
// survivors at a time into a per-wave LDS buffer. Segments combine per pixel
// via (C,T)o(C',T') = (C + T*C', T*T').
constexpr int TS = 8;
constexpr int SEGN = NPTS / 4;  // 512 per wave

__global__ __launch_bounds__(256) void rasterize_kernel(const float4* __restrict__ bounds,
                                                        const float4* __restrict__ attr,
                                                        float* __restrict__ out) {
  __shared__ unsigned short list[NPTS];   // 4KB, wave w owns [512w, 512w+len)
  __shared__ float4 stg[4][16][3];        // 3KB per-wave staging
  __shared__ float comb[4][6][64];        // 6KB [seg][field][pixel]

  int tid = threadIdx.x, wave = tid >> 6, lane = tid & 63;
  int tileX = blockIdx.x, tileY = blockIdx.y;
  // pixel centers span [tile*8+0.5, tile*8+7.5]; 0.5 slack on both sides
  float x0 = tileX * TS, x1 = tileX * TS + TS;
  float y0 = tileY * TS, y1 = tileY * TS + TS;

  // ---- per-wave cull & stable compaction ----
  int base = wave * SEGN;
  int cnt = 0;
  for (int c = 0; c < SEGN; c += 64) {
    int g = base + c + lane;
    float4 bo = bounds[g];
    // NaN radius (culled gaussian) -> comparisons false -> dropped
    bool keep = (bo.x + bo.z >= x0) && (bo.x - bo.z <= x1) &&
                (bo.y + bo.w >= y0) && (bo.y - bo.w <= y1);
    unsigned long long m = __ballot(keep);
    if (keep) list[base + cnt + __popcll(m & ((1ull << lane) - 1ull))] = (unsigned short)g;
    cnt += __popcll(m);
  }
  int L = cnt;  // wave-uniform
  __syncthreads();  // list fully built (only needed because waves share the LDS block)

  // ---- per-wave compositing, lane = pixel ----
  float pxf = tileX * TS + (lane & 7) + 0.5f;
  float pyf = tileY * TS + (lane >> 3) + 0.5f;
  float cr = 0.f, cg = 0.f, cb = 0.f, aa = 0.f, dd = 0.f, T = 1.0f;

  for (int j0 = 0; j0 < L; j0 += 16) {
    int n = min(16, L - j0);
    // stage n survivors: lane l<3n loads one float4 of survivor l/3
    if (lane < 3 * n) {
      int s = lane / 3, p = lane % 3;
      int g = (int)list[base + j0 + s];
      stg[wave][s][p] = attr[g * 3 + p];
    }
    // wave-lockstep: ensure ds_writes (and the ds_read of list) are done.
    asm volatile("s_waitcnt lgkmcnt(0)" ::: "memory");

    for (int s = 0; s < n; ++s) {
      float4 v0 = stg[wave][s][0];  // mx,my,cA,cB  (broadcast reads)
      float4 v1 = stg[wave][s][1];  // cC,op,z,r
      float4 v2 = stg[wave][s][2];  // g,b,-,-
      float dx = pxf - v0.x, dy = pyf - v0.y;
      float sigma = 0.5f * (v0.z * dx * dx + v1.x * dy * dy) + v0.w * dx * dy;
      float e = __expf(-sigma);
      float raw = v1.y * e;
      float alpha = fminf(ALPHA_CLIP, raw);
      bool use = (sigma >= 0.0f) && (raw > ALPHA_MIN);
      alpha = use ? alpha : 0.0f;
      float w = alpha * T;
      cr += w * v1.w;
      cg += w * v2.x;
      cb += w * v2.y;
      aa += w;
      dd += w * v1.z;
      T *= (1.0f - alpha);
    }
    asm volatile("s_waitcnt lgkmcnt(0)" ::: "memory");  // reads done before next overwrite
  }

  comb[wave][0][lane] = cr;
  comb[wave][1][lane] = cg;
  comb[wave][2][lane] = cb;
  comb[wave][3][lane] = aa;
  comb[wave][4][lane] = dd;
  comb[wave][5][lane] = T;
  __syncthreads();

  // ---- combine 4 ordered segments per pixel (wave 0) ----
  if (wave == 0) {
    int p = lane;
    float Cr = comb[0][0][p], Cg = comb[0][1][p], Cb = comb[0][2][p];
    float Aa = comb[0][3][p], Dd = comb[0][4][p], Tt = comb[0][5][p];
#pragma unroll
    for (int s = 1; s < 4; ++s) {
      Cr += Tt * comb[s][0][p];
      Cg += Tt * comb[s][1][p];
      Cb += Tt * comb[s][2][p];
      Aa += Tt * comb[s][3][p];
      Dd += Tt * comb[s][4][p];
      Tt *= comb[s][5][p];
    }
    int col = tileX * TS + (p & 7), row = tileY * TS + (p >> 3);
    int pix = row * HW + col;
    out[pix * 3 + 0] = Cr;
    out[pix * 3 + 1] = Cg;
    out[pix * 3 + 2] = Cb;
    out[HW * HW * 3 + pix] = Aa;
    out[HW * HW * 4 + pix] = Dd / fmaxf(Aa, 1e-10f);
  }
}

extern "C" void kernel_launch(void* const* d_in, const int* in_sizes, int n_in,
                              void* d_out, int out_size, void* d_ws, size_t ws_size,
                              hipStream_t stream) {
  const float* means = (const float*)d_in[0];
  const float* quats = (const float*)d_in[1];
  const float* scales = (const float*)d_in[2];
  const float* opacities = (const float*)d_in[3];
  const float* colors = (const float*)d_in[4];
  const float* viewmats = (const float*)d_in[5];
  const float* Ks = (const float*)d_in[6];
  float* out = (float*)d_out;
  float* ws = (float*)d_ws;

  float* key = ws;                                  // NPTS
  float4* pb = (float4*)(ws + 2048);                // NPTS
  float4* pa = (float4*)(ws + 10240);               // 3*NPTS
  float4* attr = (float4*)(ws + 34816);             // 3*NPTS
  float4* bounds = (float4*)(ws + 59392);           // NPTS

  preprocess_kernel<<<NPTS / 64, 64, 0, stream>>>(means, quats, scales, opacities, colors,
                                                  viewmats, Ks, key, pb, pa);
  sortscatter_kernel<<<NPTS / 32, 256, 0, stream>>>(key, pb, pa, bounds, attr);
  dim3 grid(HW / TS, HW / TS);
  rasterize_kernel<<<grid, 256, 0, stream>>>(bounds, attr, out);
}

// Round 6
// 14.818 us; speedup vs baseline: 6.3155x; 1.6712x over previous
//
#include <hip/hip_runtime.h>
#include <math.h>

#define HW 128
#define NPTS 2048

constexpr float ZNEAR = 0.01f, ZFAR = 100.0f;
constexpr float EPS2D = 0.3f;
constexpr float ALPHA_CLIP = 0.999f;
constexpr float ALPHA_MIN = 1.0f / 255.0f;

constexpr int TS = 8;        // tile size
constexpr int NT = 512;      // threads per block (8 waves)
constexpr int CAP = 768;     // max survivors per tile (worst tile ~100-150 for this scene)

// Fully fused single-dispatch rasterizer. One block per 8x8 tile (grid 16x16,
// 1 block/CU). Each block redundantly preprocesses all 2048 Gaussians (4 per
// thread, ~0.5us VALU), culls against its tile with the exact ellipse bound,
// compacts survivors into LDS, locally sorts them by packed (z,idx) key
// (== global stable argsort restricted to survivors), then composites with
// 8 depth segments combined via (C,T)o(C',T') = (C + T*C', T*T').
__global__ __launch_bounds__(NT) void fused_raster_kernel(
    const float* __restrict__ means, const float* __restrict__ quats,
    const float* __restrict__ scales, const float* __restrict__ opacities,
    const float* __restrict__ colors, const float* __restrict__ viewmat,
    const float* __restrict__ Kmat, float* __restrict__ out) {
  __shared__ float attr[CAP * 12];            // 36KB [mx,my,cA,cB,cC,op,z,r,g,b,-,-]
  __shared__ unsigned long long kb[CAP];      // 6KB  (zbits<<16)|gidx
  __shared__ unsigned short slist[CAP];       // 1.5KB rank -> slot
  __shared__ float comb[8][6][64];            // 12KB [seg][field][pixel]
  __shared__ int cnt;

  int tid = threadIdx.x, wave = tid >> 6, lane = tid & 63;
  int tileX = blockIdx.x, tileY = blockIdx.y;
  float x0 = tileX * TS, x1 = tileX * TS + TS;  // 0.5px slack vs pixel centers
  float y0 = tileY * TS, y1 = tileY * TS + TS;

  if (tid == 0) cnt = 0;
  __syncthreads();

  float R00 = viewmat[0], R01 = viewmat[1], R02 = viewmat[2],  t0 = viewmat[3];
  float R10 = viewmat[4], R11 = viewmat[5], R12 = viewmat[6],  t1 = viewmat[7];
  float R20 = viewmat[8], R21 = viewmat[9], R22 = viewmat[10], t2 = viewmat[11];
  float fx = Kmat[0], cx = Kmat[2], fy = Kmat[4], cy = Kmat[5];

  // ---- phase 1: preprocess + cull + compact ----
  for (int ch = 0; ch < NPTS / NT; ++ch) {
    int g = ch * NT + tid;

    float m0 = means[3 * g], m1 = means[3 * g + 1], m2 = means[3 * g + 2];
    float x = R00 * m0 + R01 * m1 + R02 * m2 + t0;
    float y = R10 * m0 + R11 * m1 + R12 * m2 + t1;
    float z = R20 * m0 + R21 * m1 + R22 * m2 + t2;
    bool valid = (z > ZNEAR) && (z < ZFAR);
    float zc = fmaxf(z, 1e-6f);

    float qw = quats[4 * g], qx = quats[4 * g + 1], qy = quats[4 * g + 2], qz = quats[4 * g + 3];
    float qn = sqrtf(qw * qw + qx * qx + qy * qy + qz * qz);
    qw /= qn; qx /= qn; qy /= qn; qz /= qn;
    float sx = scales[3 * g], sy = scales[3 * g + 1], sz = scales[3 * g + 2];

    float M00 = (1.f - 2.f * (qy * qy + qz * qz)) * sx;
    float M01 = (2.f * (qx * qy - qw * qz)) * sy;
    float M02 = (2.f * (qx * qz + qw * qy)) * sz;
    float M10 = (2.f * (qx * qy + qw * qz)) * sx;
    float M11 = (1.f - 2.f * (qx * qx + qz * qz)) * sy;
    float M12 = (2.f * (qy * qz - qw * qx)) * sz;
    float M20 = (2.f * (qx * qz - qw * qy)) * sx;
    float M21 = (2.f * (qy * qz + qw * qx)) * sy;
    float M22 = (1.f - 2.f * (qx * qx + qy * qy)) * sz;

    float C00 = M00 * M00 + M01 * M01 + M02 * M02;
    float C01 = M00 * M10 + M01 * M11 + M02 * M12;
    float C02 = M00 * M20 + M01 * M21 + M02 * M22;
    float C11 = M10 * M10 + M11 * M11 + M12 * M12;
    float C12 = M10 * M20 + M11 * M21 + M12 * M22;
    float C22 = M20 * M20 + M21 * M21 + M22 * M22;

    float B00 = R00 * C00 + R01 * C01 + R02 * C02;
    float B01 = R00 * C01 + R01 * C11 + R02 * C12;
    float B02 = R00 * C02 + R01 * C12 + R02 * C22;
    float B10 = R10 * C00 + R11 * C01 + R12 * C02;
    float B11 = R10 * C01 + R11 * C11 + R12 * C12;
    float B12 = R10 * C02 + R11 * C12 + R12 * C22;
    float B20 = R20 * C00 + R21 * C01 + R22 * C02;
    float B21 = R20 * C01 + R21 * C11 + R22 * C12;
    float B22 = R20 * C02 + R21 * C12 + R22 * C22;

    float V00 = B00 * R00 + B01 * R01 + B02 * R02;
    float V01 = B00 * R10 + B01 * R11 + B02 * R12;
    float V02 = B00 * R20 + B01 * R21 + B02 * R22;
    float V11 = B10 * R10 + B11 * R11 + B12 * R12;
    float V12 = B10 * R20 + B11 * R21 + B12 * R22;
    float V22 = B20 * R20 + B21 * R21 + B22 * R22;

    float a0 = fx / zc;
    float a2 = -fx * x / (zc * zc);
    float b1 = fy / zc;
    float b2 = -fy * y / (zc * zc);

    float c00 = a0 * a0 * V00 + 2.f * a0 * a2 * V02 + a2 * a2 * V22;
    float c01 = a0 * b1 * V01 + a0 * b2 * V02 + a2 * b1 * V12 + a2 * b2 * V22;
    float c11 = b1 * b1 * V11 + 2.f * b1 * b2 * V12 + b2 * b2 * V22;

    float a = c00 + EPS2D;
    float b = c01;
    float c = c11 + EPS2D;
    float det = a * c - b * b;
    float cA = c / det;
    float cB = -b / det;
    float cC = a / det;

    float mx = fx * x / zc + cx;
    float my = fy * y / zc + cy;
    float op = valid ? opacities[g] : 0.0f;

    // Exact cull: contribution is 0 wherever sigma >= tau = ln(255*op).
    // Ellipse {sigma <= tau}: max|dx| = sqrt(2 tau a), max|dy| = sqrt(2 tau c).
    // op <= 1/255 (incl. invalid) -> tau <= 0 -> NaN/0 radius -> culled.
    float tau = logf(255.0f * op);
    float rx = sqrtf(2.0f * tau * a);
    float ry = sqrtf(2.0f * tau * c);
    bool keep = (mx + rx >= x0) && (mx - rx <= x1) && (my + ry >= y0) && (my - ry <= y1);

    unsigned long long msk = __ballot(keep);
    int base;
    if (lane == 0) base = atomicAdd(&cnt, __popcll(msk));
    base = __shfl(base, 0);
    if (keep) {
      int slot = base + __popcll(msk & ((1ull << lane) - 1ull));
      if (slot < CAP) {
        float* A = &attr[slot * 12];
        A[0] = mx; A[1] = my; A[2] = cA; A[3] = cB;
        A[4] = cC; A[5] = op; A[6] = z;  A[7] = colors[3 * g];
        A[8] = colors[3 * g + 1]; A[9] = colors[3 * g + 2];
        // z > ZNEAR > 0 for all survivors -> float bits are order-preserving.
        kb[slot] = (((unsigned long long)__float_as_uint(z)) << 16) | (unsigned)g;
      }
    }
  }
  __syncthreads();
  int L = min(cnt, CAP);

  // ---- phase 2: local stable sort (rank count on packed keys) ----
  for (int s = tid; s < L; s += NT) {
    unsigned long long ks = kb[s];
    int r = 0;
    for (int t = 0; t < L; ++t) r += (kb[t] < ks);
    slist[r] = (unsigned short)s;
  }
  __syncthreads();

  // ---- phase 3: composite, 8 depth segments (wave = segment, lane = pixel) ----
  int s0 = (L * wave) >> 3, s1 = (L * (wave + 1)) >> 3;
  float pxf = tileX * TS + (lane & 7) + 0.5f;
  float pyf = tileY * TS + (lane >> 3) + 0.5f;
  float cr = 0.f, cg = 0.f, cb = 0.f, aa = 0.f, dd = 0.f, T = 1.0f;

  for (int j = s0; j < s1; ++j) {
    const float* A = &attr[(int)slist[j] * 12];
    float4 v0 = *reinterpret_cast<const float4*>(A);      // mx,my,cA,cB
    float4 v1 = *reinterpret_cast<const float4*>(A + 4);  // cC,op,z,r
    float2 v2 = *reinterpret_cast<const float2*>(A + 8);  // g,b
    float dx = pxf - v0.x, dy = pyf - v0.y;
    float sigma = 0.5f * (v0.z * dx * dx + v1.x * dy * dy) + v0.w * dx * dy;
    float e = __expf(-sigma);
    float raw = v1.y * e;
    float alpha = fminf(ALPHA_CLIP, raw);
    bool use = (sigma >= 0.0f) && (raw > ALPHA_MIN);
    alpha = use ? alpha : 0.0f;
    float w = alpha * T;
    cr += w * v1.w;
    cg += w * v2.x;
    cb += w * v2.y;
    aa += w;
    dd += w * v1.z;
    T *= (1.0f - alpha);
  }

  comb[wave][0][lane] = cr;
  comb[wave][1][lane] = cg;
  comb[wave][2][lane] = cb;
  comb[wave][3][lane] = aa;
  comb[wave][4][lane] = dd;
  comb[wave][5][lane] = T;
  __syncthreads();

  if (wave == 0) {
    int p = lane;
    float Cr = comb[0][0][p], Cg = comb[0][1][p], Cb = comb[0][2][p];
    float Aa = comb[0][3][p], Dd = comb[0][4][p], Tt = comb[0][5][p];
#pragma unroll
    for (int s = 1; s < 8; ++s) {
      Cr += Tt * comb[s][0][p];
      Cg += Tt * comb[s][1][p];
      Cb += Tt * comb[s][2][p];
      Aa += Tt * comb[s][3][p];
      Dd += Tt * comb[s][4][p];
      Tt *= comb[s][5][p];
    }
    int col = tileX * TS + (p & 7), row = tileY * TS + (p >> 3);
    int pix = row * HW + col;
    out[pix * 3 + 0] = Cr;
    out[pix * 3 + 1] = Cg;
    out[pix * 3 + 2] = Cb;
    out[HW * HW * 3 + pix] = Aa;
    out[HW * HW * 4 + pix] = Dd / fmaxf(Aa, 1e-10f);
  }
}

extern "C" void kernel_launch(void* const* d_in, const int* in_sizes, int n_in,
                              void* d_out, int out_size, void* d_ws, size_t ws_size,
                              hipStream_t stream) {
  const float* means = (const float*)d_in[0];
  const float* quats = (const float*)d_in[1];
  const float* scales = (const float*)d_in[2];
  const float* opacities = (const float*)d_in[3];
  const float* colors = (const float*)d_in[4];
  const float* viewmats = (const float*)d_in[5];
  const float* Ks = (const float*)d_in[6];
  float* out = (float*)d_out;

  dim3 grid(HW / TS, HW / TS);
  fused_raster_kernel<<<grid, NT, 0, stream>>>(means, quats, scales, opacities, colors,
                                               viewmats, Ks, out);
}

// Round 7
// 11.780 us; speedup vs baseline: 7.9446x; 1.2580x over previous
//
#include <hip/hip_runtime.h>
#include <math.h>

#define HW 128
#define NPTS 2048

constexpr float ZNEAR = 0.01f, ZFAR = 100.0f;
constexpr float EPS2D = 0.3f;
constexpr float ALPHA_CLIP = 0.999f;
constexpr float ALPHA_MIN = 1.0f / 255.0f;

constexpr int TS = 8;         // tile size
constexpr int NT = 512;       // threads per block (8 waves)
constexpr int CAP = 768;      // max exact survivors per tile (worst ~150 here)
constexpr int CCAP = NPTS;    // candidate list can never overflow

// Fully fused single-dispatch rasterizer, one block per 8x8 tile (grid 16x16).
// Pass A: cheap conservative cull of all 2048 (transform + radius bound from
//         lambda_max(cov3) = max s_i^2 -- never false-culls).
// Pass B: full projection/conic math on candidates only, exact ellipse cull,
//         compact into LDS.
// Then: local stable sort by packed (z,idx) key (== global stable argsort
// restricted to survivors), composite with 8 depth segments combined via
// (C,T) o (C',T') = (C + T*C', T*T').
__global__ __launch_bounds__(NT) void fused_raster_kernel(
    const float* __restrict__ means, const float* __restrict__ quats,
    const float* __restrict__ scales, const float* __restrict__ opacities,
    const float* __restrict__ colors, const float* __restrict__ viewmat,
    const float* __restrict__ Kmat, float* __restrict__ out) {
  __shared__ float attr[CAP * 12];            // 36KB [mx,my,cA,cB,cC,op,z,r,g,b,-,-]
  __shared__ unsigned long long kb[CAP];      // 6KB  (zbits<<16)|gidx
  __shared__ unsigned short slist[CAP];       // 1.5KB rank -> slot
  __shared__ unsigned short cand[CCAP];       // 4KB candidate gaussian ids
  __shared__ float comb[8][6][64];            // 12KB [seg][field][pixel]
  __shared__ int cnt, ccnt;

  int tid = threadIdx.x, wave = tid >> 6, lane = tid & 63;
  int tileX = blockIdx.x, tileY = blockIdx.y;
  float x0 = tileX * TS, x1 = tileX * TS + TS;  // 0.5px slack vs pixel centers
  float y0 = tileY * TS, y1 = tileY * TS + TS;

  if (tid == 0) { cnt = 0; ccnt = 0; }
  __syncthreads();

  float R00 = viewmat[0], R01 = viewmat[1], R02 = viewmat[2],  t0 = viewmat[3];
  float R10 = viewmat[4], R11 = viewmat[5], R12 = viewmat[6],  t1 = viewmat[7];
  float R20 = viewmat[8], R21 = viewmat[9], R22 = viewmat[10], t2 = viewmat[11];
  float fx = Kmat[0], cx = Kmat[2], fy = Kmat[4], cy = Kmat[5];

  // ---- pass A: cheap conservative cull (means/scales/opac only) ----
  for (int ch = 0; ch < NPTS / NT; ++ch) {
    int g = ch * NT + tid;
    float m0 = means[3 * g], m1 = means[3 * g + 1], m2 = means[3 * g + 2];
    float x = R00 * m0 + R01 * m1 + R02 * m2 + t0;
    float y = R10 * m0 + R11 * m1 + R12 * m2 + t1;
    float z = R20 * m0 + R21 * m1 + R22 * m2 + t2;
    bool valid = (z > ZNEAR) && (z < ZFAR);
    float zc = fmaxf(z, 1e-6f);
    float izc = 1.0f / zc;
    float op = valid ? opacities[g] : 0.0f;
    float tau = logf(255.0f * op);  // <=0 or NaN -> culled below

    float sx = scales[3 * g], sy = scales[3 * g + 1], sz = scales[3 * g + 2];
    float smax2 = fmaxf(fmaxf(sx * sx, sy * sy), sz * sz);

    float mx = fx * x * izc + cx;
    float my = fy * y * izc + cy;
    float xz = x * izc, yz = y * izc;
    float j0sq = (fx * izc) * (fx * izc) * (1.0f + xz * xz);  // |J row0|^2
    float j1sq = (fy * izc) * (fy * izc) * (1.0f + yz * yz);  // |J row1|^2
    // a_exact <= j0sq*smax2 + EPS2D  (lambda_max(covc) = max s_i^2)
    float rxb = sqrtf(2.0f * tau * (j0sq * smax2 + EPS2D)) * 1.0001f;
    float ryb = sqrtf(2.0f * tau * (j1sq * smax2 + EPS2D)) * 1.0001f;
    bool keep = (mx + rxb >= x0) && (mx - rxb <= x1) &&
                (my + ryb >= y0) && (my - ryb <= y1);  // NaN -> false
    if (keep) {
      int slot = atomicAdd(&ccnt, 1);  // wave-coalesced by compiler
      cand[slot] = (unsigned short)g;
    }
  }
  __syncthreads();
  int NC = min(ccnt, CCAP);

  // ---- pass B: full math + exact cull on candidates ----
  for (int s = tid; s < NC; s += NT) {
    int g = (int)cand[s];
    float m0 = means[3 * g], m1 = means[3 * g + 1], m2 = means[3 * g + 2];
    float x = R00 * m0 + R01 * m1 + R02 * m2 + t0;
    float y = R10 * m0 + R11 * m1 + R12 * m2 + t1;
    float z = R20 * m0 + R21 * m1 + R22 * m2 + t2;
    bool valid = (z > ZNEAR) && (z < ZFAR);
    float zc = fmaxf(z, 1e-6f);
    float izc = 1.0f / zc;

    float qw = quats[4 * g], qx = quats[4 * g + 1], qy = quats[4 * g + 2], qz = quats[4 * g + 3];
    float qn = sqrtf(qw * qw + qx * qx + qy * qy + qz * qz);
    qw /= qn; qx /= qn; qy /= qn; qz /= qn;
    float sx = scales[3 * g], sy = scales[3 * g + 1], sz = scales[3 * g + 2];

    // M = rotmat(q) with columns scaled by s
    float M00 = (1.f - 2.f * (qy * qy + qz * qz)) * sx;
    float M01 = (2.f * (qx * qy - qw * qz)) * sy;
    float M02 = (2.f * (qx * qz + qw * qy)) * sz;
    float M10 = (2.f * (qx * qy + qw * qz)) * sx;
    float M11 = (1.f - 2.f * (qx * qx + qz * qz)) * sy;
    float M12 = (2.f * (qy * qz - qw * qx)) * sz;
    float M20 = (2.f * (qx * qz - qw * qy)) * sx;
    float M21 = (2.f * (qy * qz + qw * qx)) * sy;
    float M22 = (1.f - 2.f * (qx * qx + qy * qy)) * sz;

    // P = J * R (2x3); J rows (a0,0,a2),(0,b1,b2)
    float a0 = fx * izc;
    float a2 = -fx * x * izc * izc;
    float b1 = fy * izc;
    float b2 = -fy * y * izc * izc;
    float P00 = a0 * R00 + a2 * R20, P01 = a0 * R01 + a2 * R21, P02 = a0 * R02 + a2 * R22;
    float P10 = b1 * R10 + b2 * R20, P11 = b1 * R11 + b2 * R21, P12 = b1 * R12 + b2 * R22;
    // U = P * M (2x3); cov2 = U U^T
    float U00 = P00 * M00 + P01 * M10 + P02 * M20;
    float U01 = P00 * M01 + P01 * M11 + P02 * M21;
    float U02 = P00 * M02 + P01 * M12 + P02 * M22;
    float U10 = P10 * M00 + P11 * M10 + P12 * M20;
    float U11 = P10 * M01 + P11 * M11 + P12 * M21;
    float U12 = P10 * M02 + P11 * M12 + P12 * M22;
    float c00 = U00 * U00 + U01 * U01 + U02 * U02;
    float c01 = U00 * U10 + U01 * U11 + U02 * U12;
    float c11 = U10 * U10 + U11 * U11 + U12 * U12;

    float a = c00 + EPS2D;
    float b = c01;
    float c = c11 + EPS2D;
    float det = a * c - b * b;
    float cA = c / det;
    float cB = -b / det;
    float cC = a / det;

    float mx = fx * x * izc + cx;
    float my = fy * y * izc + cy;
    float op = valid ? opacities[g] : 0.0f;

    // Exact cull: zero contribution wherever sigma >= tau = ln(255*op).
    float tau = logf(255.0f * op);
    float rx = sqrtf(2.0f * tau * a);
    float ry = sqrtf(2.0f * tau * c);
    bool keep = (mx + rx >= x0) && (mx - rx <= x1) &&
                (my + ry >= y0) && (my - ry <= y1);  // NaN -> false
    if (keep) {
      int slot = atomicAdd(&cnt, 1);
      if (slot < CAP) {
        float* A = &attr[slot * 12];
        A[0] = mx; A[1] = my; A[2] = cA; A[3] = cB;
        A[4] = cC; A[5] = op; A[6] = z;  A[7] = colors[3 * g];
        A[8] = colors[3 * g + 1]; A[9] = colors[3 * g + 2];
        // z > ZNEAR > 0 -> float bits order-preserving; idx breaks ties stably.
        kb[slot] = (((unsigned long long)__float_as_uint(z)) << 16) | (unsigned)g;
      }
    }
  }
  __syncthreads();
  int L = min(cnt, CAP);

  // ---- local stable sort (rank count on packed keys) ----
  for (int s = tid; s < L; s += NT) {
    unsigned long long ks = kb[s];
    int r = 0;
    for (int t = 0; t < L; ++t) r += (kb[t] < ks);
    slist[r] = (unsigned short)s;
  }
  __syncthreads();

  // ---- composite: 8 depth segments (wave = segment, lane = pixel) ----
  int s0 = (L * wave) >> 3, s1 = (L * (wave + 1)) >> 3;
  float pxf = tileX * TS + (lane & 7) + 0.5f;
  float pyf = tileY * TS + (lane >> 3) + 0.5f;
  float cr = 0.f, cg = 0.f, cb = 0.f, aa = 0.f, dd = 0.f, T = 1.0f;

  for (int j = s0; j < s1; ++j) {
    const float* A = &attr[(int)slist[j] * 12];
    float4 v0 = *reinterpret_cast<const float4*>(A);      // mx,my,cA,cB
    float4 v1 = *reinterpret_cast<const float4*>(A + 4);  // cC,op,z,r
    float2 v2 = *reinterpret_cast<const float2*>(A + 8);  // g,b
    float dx = pxf - v0.x, dy = pyf - v0.y;
    float sigma = 0.5f * (v0.z * dx * dx + v1.x * dy * dy) + v0.w * dx * dy;
    float e = __expf(-sigma);
    float raw = v1.y * e;
    float alpha = fminf(ALPHA_CLIP, raw);
    bool use = (sigma >= 0.0f) && (raw > ALPHA_MIN);
    alpha = use ? alpha : 0.0f;
    float w = alpha * T;
    cr += w * v1.w;
    cg += w * v2.x;
    cb += w * v2.y;
    aa += w;
    dd += w * v1.z;
    T *= (1.0f - alpha);
  }

  comb[wave][0][lane] = cr;
  comb[wave][1][lane] = cg;
  comb[wave][2][lane] = cb;
  comb[wave][3][lane] = aa;
  comb[wave][4][lane] = dd;
  comb[wave][5][lane] = T;
  __syncthreads();

  if (wave == 0) {
    int p = lane;
    float Cr = comb[0][0][p], Cg = comb[0][1][p], Cb = comb[0][2][p];
    float Aa = comb[0][3][p], Dd = comb[0][4][p], Tt = comb[0][5][p];
#pragma unroll
    for (int s = 1; s < 8; ++s) {
      Cr += Tt * comb[s][0][p];
      Cg += Tt * comb[s][1][p];
      Cb += Tt * comb[s][2][p];
      Aa += Tt * comb[s][3][p];
      Dd += Tt * comb[s][4][p];
      Tt *= comb[s][5][p];
    }
    int col = tileX * TS + (p & 7), row = tileY * TS + (p >> 3);
    int pix = row * HW + col;
    out[pix * 3 + 0] = Cr;
    out[pix * 3 + 1] = Cg;
    out[pix * 3 + 2] = Cb;
    out[HW * HW * 3 + pix] = Aa;
    out[HW * HW * 4 + pix] = Dd / fmaxf(Aa, 1e-10f);
  }
}

extern "C" void kernel_launch(void* const* d_in, const int* in_sizes, int n_in,
                              void* d_out, int out_size, void* d_ws, size_t ws_size,
                              hipStream_t stream) {
  const float* means = (const float*)d_in[0];
  const float* quats = (const float*)d_in[1];
  const float* scales = (const float*)d_in[2];
  const float* opacities = (const float*)d_in[3];
  const float* colors = (const float*)d_in[4];
  const float* viewmats = (const float*)d_in[5];
  const float* Ks = (const float*)d_in[6];
  float* out = (float*)d_out;

  dim3 grid(HW / TS, HW / TS);
  fused_raster_kernel<<<grid, NT, 0, stream>>>(means, quats, scales, opacities, colors,
                                               viewmats, Ks, out);
}

// Round 8
// 11.650 us; speedup vs baseline: 8.0332x; 1.0112x over previous
//
#include <hip/hip_runtime.h>
#include <math.h>

#define HW 128
#define NPTS 2048

constexpr float ZNEAR = 0.01f, ZFAR = 100.0f;
constexpr float EPS2D = 0.3f;
constexpr float ALPHA_CLIP = 0.999f;
constexpr float ALPHA_MIN = 1.0f / 255.0f;
constexpr float TAUMAX = 5.55f;  // >= ln(255*op) for any op <= 1.0 (conservative)

constexpr int TS = 8;         // tile size
constexpr int NT = 512;       // threads per block (8 waves)
constexpr int CAP = 768;      // max exact survivors per tile (worst ~150-400 here)
constexpr int CCAP = NPTS;    // candidate list can never overflow

// Fully fused single-dispatch rasterizer, one block per 8x8 tile (grid 16x16).
// Pass A: cheap conservative cull of all 2048 — transform + squared-distance
//         test against radius bound from lambda_max(cov3) = max s_i^2 and
//         tau <= TAUMAX. Never false-culls (bound is strictly >= exact radius).
// Pass B: full projection/conic math on candidates only, exact ellipse cull
//         (squared form), compact into LDS.
// Then: local stable sort by packed (z,idx) key (== global stable argsort
// restricted to survivors), composite with 8 depth segments combined via
// (C,T) o (C',T') = (C + T*C', T*T').
__global__ __launch_bounds__(NT) void fused_raster_kernel(
    const float* __restrict__ means, const float* __restrict__ quats,
    const float* __restrict__ scales, const float* __restrict__ opacities,
    const float* __restrict__ colors, const float* __restrict__ viewmat,
    const float* __restrict__ Kmat, float* __restrict__ out) {
  __shared__ float attr[CAP * 12];            // 36KB [mx,my,cA,cB,cC,op,z,r,g,b,-,-]
  __shared__ unsigned long long kb[CAP];      // 6KB  (zbits<<16)|gidx
  __shared__ unsigned short slist[CAP];       // 1.5KB rank -> slot
  __shared__ unsigned short cand[CCAP];       // 4KB candidate gaussian ids
  __shared__ float comb[8][6][64];            // 12KB [seg][field][pixel]
  __shared__ int cnt, ccnt;

  int tid = threadIdx.x, wave = tid >> 6, lane = tid & 63;
  int tileX = blockIdx.x, tileY = blockIdx.y;
  float x0 = tileX * TS, x1 = tileX * TS + TS;  // 0.5px slack vs pixel centers
  float y0 = tileY * TS, y1 = tileY * TS + TS;

  if (tid == 0) { cnt = 0; ccnt = 0; }
  __syncthreads();

  float R00 = viewmat[0], R01 = viewmat[1], R02 = viewmat[2],  t0 = viewmat[3];
  float R10 = viewmat[4], R11 = viewmat[5], R12 = viewmat[6],  t1 = viewmat[7];
  float R20 = viewmat[8], R21 = viewmat[9], R22 = viewmat[10], t2 = viewmat[11];
  float fx = Kmat[0], cx = Kmat[2], fy = Kmat[4], cy = Kmat[5];

  // ---- pass A: cheap conservative cull (no log, no sqrt) ----
  for (int ch = 0; ch < NPTS / NT; ++ch) {
    int g = ch * NT + tid;
    float m0 = means[3 * g], m1 = means[3 * g + 1], m2 = means[3 * g + 2];
    float x = R00 * m0 + R01 * m1 + R02 * m2 + t0;
    float y = R10 * m0 + R11 * m1 + R12 * m2 + t1;
    float z = R20 * m0 + R21 * m1 + R22 * m2 + t2;
    bool valid = (z > ZNEAR) && (z < ZFAR);
    float zc = fmaxf(z, 1e-6f);
    float izc = 1.0f / zc;
    float op = opacities[g];

    float sx = scales[3 * g], sy = scales[3 * g + 1], sz = scales[3 * g + 2];
    float smax2 = fmaxf(fmaxf(sx * sx, sy * sy), sz * sz);

    float mx = fx * x * izc + cx;
    float my = fy * y * izc + cy;
    float xz = x * izc, yz = y * izc;
    float j0sq = (fx * izc) * (fx * izc) * (1.0f + xz * xz);  // |J row0|^2
    float j1sq = (fy * izc) * (fy * izc) * (1.0f + yz * yz);  // |J row1|^2
    // exact rx^2 = 2 tau a <= 2*TAUMAX*(j0sq*smax2 + EPS2D)
    float rxb2 = 2.0f * TAUMAX * (j0sq * smax2 + EPS2D) * 1.0002f;
    float ryb2 = 2.0f * TAUMAX * (j1sq * smax2 + EPS2D) * 1.0002f;
    float dxo = fmaxf(fmaxf(x0 - mx, mx - x1), 0.0f);  // dist(mx, [x0,x1])
    float dyo = fmaxf(fmaxf(y0 - my, my - y1), 0.0f);
    bool keep = valid && (op > ALPHA_MIN) &&
                (dxo * dxo <= rxb2) && (dyo * dyo <= ryb2);  // NaN -> false
    if (keep) {
      int slot = atomicAdd(&ccnt, 1);  // wave-coalesced by compiler
      cand[slot] = (unsigned short)g;
    }
  }
  __syncthreads();
  int NC = min(ccnt, CCAP);

  // ---- pass B: full math + exact cull on candidates ----
  for (int s = tid; s < NC; s += NT) {
    int g = (int)cand[s];
    float m0 = means[3 * g], m1 = means[3 * g + 1], m2 = means[3 * g + 2];
    float x = R00 * m0 + R01 * m1 + R02 * m2 + t0;
    float y = R10 * m0 + R11 * m1 + R12 * m2 + t1;
    float z = R20 * m0 + R21 * m1 + R22 * m2 + t2;
    bool valid = (z > ZNEAR) && (z < ZFAR);
    float zc = fmaxf(z, 1e-6f);
    float izc = 1.0f / zc;

    float qw = quats[4 * g], qx = quats[4 * g + 1], qy = quats[4 * g + 2], qz = quats[4 * g + 3];
    float qn = sqrtf(qw * qw + qx * qx + qy * qy + qz * qz);
    qw /= qn; qx /= qn; qy /= qn; qz /= qn;
    float sx = scales[3 * g], sy = scales[3 * g + 1], sz = scales[3 * g + 2];

    // M = rotmat(q) with columns scaled by s
    float M00 = (1.f - 2.f * (qy * qy + qz * qz)) * sx;
    float M01 = (2.f * (qx * qy - qw * qz)) * sy;
    float M02 = (2.f * (qx * qz + qw * qy)) * sz;
    float M10 = (2.f * (qx * qy + qw * qz)) * sx;
    float M11 = (1.f - 2.f * (qx * qx + qz * qz)) * sy;
    float M12 = (2.f * (qy * qz - qw * qx)) * sz;
    float M20 = (2.f * (qx * qz - qw * qy)) * sx;
    float M21 = (2.f * (qy * qz + qw * qx)) * sy;
    float M22 = (1.f - 2.f * (qx * qx + qy * qy)) * sz;

    // P = J * R (2x3); J rows (a0,0,a2),(0,b1,b2)
    float a0 = fx * izc;
    float a2 = -fx * x * izc * izc;
    float b1 = fy * izc;
    float b2 = -fy * y * izc * izc;
    float P00 = a0 * R00 + a2 * R20, P01 = a0 * R01 + a2 * R21, P02 = a0 * R02 + a2 * R22;
    float P10 = b1 * R10 + b2 * R20, P11 = b1 * R11 + b2 * R21, P12 = b1 * R12 + b2 * R22;
    // U = P * M (2x3); cov2 = U U^T
    float U00 = P00 * M00 + P01 * M10 + P02 * M20;
    float U01 = P00 * M01 + P01 * M11 + P02 * M21;
    float U02 = P00 * M02 + P01 * M12 + P02 * M22;
    float U10 = P10 * M00 + P11 * M10 + P12 * M20;
    float U11 = P10 * M01 + P11 * M11 + P12 * M21;
    float U12 = P10 * M02 + P11 * M12 + P12 * M22;
    float c00 = U00 * U00 + U01 * U01 + U02 * U02;
    float c01 = U00 * U10 + U01 * U11 + U02 * U12;
    float c11 = U10 * U10 + U11 * U11 + U12 * U12;

    float a = c00 + EPS2D;
    float b = c01;
    float c = c11 + EPS2D;
    float det = a * c - b * b;
    float cA = c / det;
    float cB = -b / det;
    float cC = a / det;

    float mx = fx * x * izc + cx;
    float my = fy * y * izc + cy;
    float op = valid ? opacities[g] : 0.0f;

    // Exact cull (squared): zero contribution wherever sigma >= tau = ln(255*op).
    float tau = logf(255.0f * op);
    float rx2 = 2.0f * tau * a;   // NaN/neg if op <= 1/255 -> culled
    float ry2 = 2.0f * tau * c;
    float dxo = fmaxf(fmaxf(x0 - mx, mx - x1), 0.0f);
    float dyo = fmaxf(fmaxf(y0 - my, my - y1), 0.0f);
    bool keep = (dxo * dxo <= rx2) && (dyo * dyo <= ry2);  // NaN -> false
    if (keep) {
      int slot = atomicAdd(&cnt, 1);
      if (slot < CAP) {
        float* A = &attr[slot * 12];
        A[0] = mx; A[1] = my; A[2] = cA; A[3] = cB;
        A[4] = cC; A[5] = op; A[6] = z;  A[7] = colors[3 * g];
        A[8] = colors[3 * g + 1]; A[9] = colors[3 * g + 2];
        // z > ZNEAR > 0 -> float bits order-preserving; idx breaks ties stably.
        kb[slot] = (((unsigned long long)__float_as_uint(z)) << 16) | (unsigned)g;
      }
    }
  }
  __syncthreads();
  int L = min(cnt, CAP);

  // ---- local stable sort (rank count on packed keys) ----
  for (int s = tid; s < L; s += NT) {
    unsigned long long ks = kb[s];
    int r = 0;
    for (int t = 0; t < L; ++t) r += (kb[t] < ks);
    slist[r] = (unsigned short)s;
  }
  __syncthreads();

  // ---- composite: 8 depth segments (wave = segment, lane = pixel) ----
  int s0 = (L * wave) >> 3, s1 = (L * (wave + 1)) >> 3;
  float pxf = tileX * TS + (lane & 7) + 0.5f;
  float pyf = tileY * TS + (lane >> 3) + 0.5f;
  float cr = 0.f, cg = 0.f, cb = 0.f, aa = 0.f, dd = 0.f, T = 1.0f;

  for (int j = s0; j < s1; ++j) {
    const float* A = &attr[(int)slist[j] * 12];
    float4 v0 = *reinterpret_cast<const float4*>(A);      // mx,my,cA,cB
    float4 v1 = *reinterpret_cast<const float4*>(A + 4);  // cC,op,z,r
    float2 v2 = *reinterpret_cast<const float2*>(A + 8);  // g,b
    float dx = pxf - v0.x, dy = pyf - v0.y;
    float sigma = 0.5f * (v0.z * dx * dx + v1.x * dy * dy) + v0.w * dx * dy;
    float e = __expf(-sigma);
    float raw = v1.y * e;
    float alpha = fminf(ALPHA_CLIP, raw);
    bool use = (sigma >= 0.0f) && (raw > ALPHA_MIN);
    alpha = use ? alpha : 0.0f;
    float w = alpha * T;
    cr += w * v1.w;
    cg += w * v2.x;
    cb += w * v2.y;
    aa += w;
    dd += w * v1.z;
    T *= (1.0f - alpha);
  }

  comb[wave][0][lane] = cr;
  comb[wave][1][lane] = cg;
  comb[wave][2][lane] = cb;
  comb[wave][3][lane] = aa;
  comb[wave][4][lane] = dd;
  comb[wave][5][lane] = T;
  __syncthreads();

  if (wave == 0) {
    int p = lane;
    float Cr = comb[0][0][p], Cg = comb[0][1][p], Cb = comb[0][2][p];
    float Aa = comb[0][3][p], Dd = comb[0][4][p], Tt = comb[0][5][p];
#pragma unroll
    for (int s = 1; s < 8; ++s) {
      Cr += Tt * comb[s][0][p];
      Cg += Tt * comb[s][1][p];
      Cb += Tt * comb[s][2][p];
      Aa += Tt * comb[s][3][p];
      Dd += Tt * comb[s][4][p];
      Tt *= comb[s][5][p];
    }
    int col = tileX * TS + (p & 7), row = tileY * TS + (p >> 3);
    int pix = row * HW + col;
    out[pix * 3 + 0] = Cr;
    out[pix * 3 + 1] = Cg;
    out[pix * 3 + 2] = Cb;
    out[HW * HW * 3 + pix] = Aa;
    out[HW * HW * 4 + pix] = Dd / fmaxf(Aa, 1e-10f);
  }
}

extern "C" void kernel_launch(void* const* d_in, const int* in_sizes, int n_in,
                              void* d_out, int out_size, void* d_ws, size_t ws_size,
                              hipStream_t stream) {
  const float* means = (const float*)d_in[0];
  const float* quats = (const float*)d_in[1];
  const float* scales = (const float*)d_in[2];
  const float* opacities = (const float*)d_in[3];
  const float* colors = (const float*)d_in[4];
  const float* viewmats = (const float*)d_in[5];
  const float* Ks = (const float*)d_in[6];
  float* out = (float*)d_out;

  dim3 grid(HW / TS, HW / TS);
  fused_raster_kernel<<<grid, NT, 0, stream>>>(means, quats, scales, opacities, colors,
                                               viewmats, Ks, out);
}